// Round 10
// baseline (169.769 us; speedup 1.0000x reference)
//
#include <hip/hip_runtime.h>
#include <hip/hip_bf16.h>

typedef __attribute__((ext_vector_type(4))) float f32x4;
typedef __attribute__((ext_vector_type(16))) float f32x16;
typedef __attribute__((ext_vector_type(8))) __bf16 bf16x8;
typedef unsigned short u16;
typedef unsigned int u32;
typedef __attribute__((ext_vector_type(4))) u16 u16x4;

// ---------- helpers ----------
__device__ __forceinline__ u16 f2bf(float f) {
    u32 u = __builtin_bit_cast(u32, f);
    u32 r = (u + 0x7FFFu + ((u >> 16) & 1u)) >> 16;
    return (u16)r;
}
__device__ __forceinline__ float bf2f(u16 h) {
    return __builtin_bit_cast(float, ((u32)h) << 16);
}
__device__ __forceinline__ bf16x8 ld_frag(const u16* p) {
    uint4 v = *reinterpret_cast<const uint4*>(p);
    return __builtin_bit_cast(bf16x8, v);
}
__device__ __forceinline__ void gld_lds(const u16* gp, u16* lp) {
    __builtin_amdgcn_global_load_lds(
        (const __attribute__((address_space(1))) u32*)gp,
        (__attribute__((address_space(3))) u32*)lp, 16, 0, 0);
}
__device__ __forceinline__ u32 pk_bf16(float lo, float hi) {
    u32 r;
    asm("v_cvt_pk_bf16_f32 %0, %1, %2" : "=v"(r) : "v"(lo), "v"(hi));
    return r;
}
__device__ __forceinline__ void unp8(uint4 v, float* f) {
    f[0] = bf2f((u16)(v.x & 0xffffu)); f[1] = bf2f((u16)(v.x >> 16));
    f[2] = bf2f((u16)(v.y & 0xffffu)); f[3] = bf2f((u16)(v.y >> 16));
    f[4] = bf2f((u16)(v.z & 0xffffu)); f[5] = bf2f((u16)(v.z >> 16));
    f[6] = bf2f((u16)(v.w & 0xffffu)); f[7] = bf2f((u16)(v.w >> 16));
}

// ---------- fused fp32 -> bf16 convert for x / qkv_w / c_proj_w ----------
__global__ __launch_bounds__(256) void cvt3(const float* __restrict__ x,
                                            const float* __restrict__ w,
                                            const float* __restrict__ c,
                                            u16* __restrict__ xb,
                                            u16* __restrict__ wb,
                                            u16* __restrict__ cb) {
    int b = blockIdx.x;
    const float* in;
    u16* out;
    int i;
    if (b < 4096)      { in = x; out = xb; i = b * 256 + threadIdx.x; }
    else if (b < 7168) { in = w; out = wb; i = (b - 4096) * 256 + threadIdx.x; }
    else               { in = c; out = cb; i = (b - 7168) * 256 + threadIdx.x; }
    float4 v = reinterpret_cast<const float4*>(in)[i];
    u16x4 o;
    o.x = f2bf(v.x); o.y = f2bf(v.y); o.z = f2bf(v.z); o.w = f2bf(v.w);
    *reinterpret_cast<u16x4*>(out + 4 * (size_t)i) = o;
}

// ---------- rope tables: ctab/stab [T=4096][64] fp32 ----------
__global__ __launch_bounds__(256) void rope_tab(float* __restrict__ ctab,
                                                float* __restrict__ stab) {
    int i = blockIdx.x * 256 + threadIdx.x;
    int t = i >> 6, j = i & 63;
    float c = 1.0f, s = 0.0f;
    if (j < 32) {
        float f = exp2f(-10.0f * (float)j / 31.0f);
        float th = (float)t * f;
        c = cosf(th); s = sinf(th);
    }
    ctab[i] = c; stab[i] = s;
}

// ---------- NT GEMM: C[M][N] = A[M][K] * B[N][K]^T, bf16 in, fp32 acc ----------
template <bool OUT_BF16>
__global__ __launch_bounds__(256) void gemm_nt(const u16* __restrict__ A,
                                               const u16* __restrict__ B,
                                               void* __restrict__ Cout,
                                               int M, int N, int K, int ldc) {
    __shared__ u16 sA[2][128 * 32];
    __shared__ u16 sB[2][128 * 32];
    const int tid = threadIdx.x;
    const int w = tid >> 6, l = tid & 63;
    const int mb = M >> 7;
    const int bm = blockIdx.x % mb, bn = blockIdx.x / mb;
    const int g = l >> 4, c16 = l & 15;
    const int srow = l >> 2, ssl = l & 3;
    const int wr = w >> 1, wc = w & 1;

    f32x4 acc[4][4] = {};

    auto stage = [&](int bi, int kt) {
#pragma unroll
        for (int cc = 0; cc < 2; ++cc) {
            int c = 2 * w + cc;
            int r = 16 * c + srow;
            int gs = ssl ^ ((r >> 1) & 3);
            gld_lds(A + (size_t)(bm * 128 + r) * K + kt * 32 + gs * 8, &sA[bi][c * 512]);
            gld_lds(B + (size_t)(bn * 128 + r) * K + kt * 32 + gs * 8, &sB[bi][c * 512]);
        }
    };

    const int NT = K >> 5;
    stage(0, 0);
    __syncthreads();
    for (int kt = 0; kt < NT; ++kt) {
        int cur = kt & 1;
        if (kt + 1 < NT) stage(cur ^ 1, kt + 1);
        bf16x8 af[4], bf[4];
#pragma unroll
        for (int mi = 0; mi < 4; ++mi) {
            int r = wr * 64 + mi * 16 + c16;
            int sl = g ^ ((r >> 1) & 3);
            af[mi] = ld_frag(&sA[cur][r * 32 + sl * 8]);
        }
#pragma unroll
        for (int ni = 0; ni < 4; ++ni) {
            int r = wc * 64 + ni * 16 + c16;
            int sl = g ^ ((r >> 1) & 3);
            bf[ni] = ld_frag(&sB[cur][r * 32 + sl * 8]);
        }
#pragma unroll
        for (int mi = 0; mi < 4; ++mi)
#pragma unroll
            for (int ni = 0; ni < 4; ++ni)
                acc[mi][ni] = __builtin_amdgcn_mfma_f32_16x16x32_bf16(
                    af[mi], bf[ni], acc[mi][ni], 0, 0, 0);
        __syncthreads();
    }
#pragma unroll
    for (int mi = 0; mi < 4; ++mi) {
#pragma unroll
        for (int ni = 0; ni < 4; ++ni) {
            int col = bn * 128 + wc * 64 + ni * 16 + c16;
            int row0 = bm * 128 + wr * 64 + mi * 16 + g * 4;
#pragma unroll
            for (int r = 0; r < 4; ++r) {
                if (OUT_BF16)
                    ((u16*)Cout)[(size_t)(row0 + r) * ldc + col] = f2bf(acc[mi][ni][r]);
                else
                    ((float*)Cout)[(size_t)(row0 + r) * ldc + col] = acc[mi][ni][r];
            }
        }
    }
}

// ---------- prep: rmsnorm+rope on q,k (q pre-scaled by ATTN_SCALE); v-mix ----------
// Qb,Kb: [H][T][128] bf16 ; Vt: [H][128][T] bf16 with tokens PERMUTED within
// each 64-block: bits 2<->3 swapped, matching the 32x32x16 MFMA A/B k-slot
// correspondence so attn's in-register P is a valid PV B-operand.
__global__ __launch_bounds__(256) void prep(const u16* __restrict__ qkvb,
                                            const float* __restrict__ ve,
                                            const float* __restrict__ lambdas,
                                            const float* __restrict__ ctab,
                                            const float* __restrict__ stab,
                                            u16* __restrict__ Qb, u16* __restrict__ Kb,
                                            u16* __restrict__ Vt) {
    __shared__ u16 sV[128 * 72];
    const int h = blockIdx.x >> 6, tb = blockIdx.x & 63;
    const int tid = threadIdx.x;
    const int trow = tid >> 2, p = tid & 3;
    const int t = tb * 64 + trow;
    const float l0 = lambdas[0], l1 = lambdas[1];
    // swap bits 2 and 3 of token index within the 64-block
    const int cperm = (trow & 51) | ((trow & 4) << 1) | ((trow & 8) >> 1);

#pragma unroll
    for (int which = 0; which < 2; ++which) {
        const u16* src = qkvb + (size_t)t * 3072 + which * 1024 + h * 128;
        int j0 = p * 16;
        float x1[16], x2[16];
        unp8(*(const uint4*)(src + j0), x1);
        unp8(*(const uint4*)(src + j0 + 8), x1 + 8);
        unp8(*(const uint4*)(src + 64 + j0), x2);
        unp8(*(const uint4*)(src + 64 + j0 + 8), x2 + 8);
        float ss = 0.0f;
#pragma unroll
        for (int e = 0; e < 16; ++e) ss += x1[e] * x1[e] + x2[e] * x2[e];
        ss += __shfl_xor(ss, 1);
        ss += __shfl_xor(ss, 2);
        float rs = rsqrtf(ss * (1.0f / 128.0f) + 1.1920929e-07f);
        float scl = which ? 1.0f : 0.12f;
        rs *= scl;
        u16* dst = (which ? Kb : Qb) + ((size_t)h * 4096 + t) * 128;
#pragma unroll
        for (int e = 0; e < 16; ++e) {
            int j = j0 + e;
            float c = ctab[t * 64 + j], s = stab[t * 64 + j];
            float a = x1[e] * rs, b = x2[e] * rs;
            dst[j] = f2bf(a * c + b * s);
            dst[j + 64] = f2bf(b * c - a * s);
        }
    }
    {
        const u16* vsrc = qkvb + (size_t)t * 3072 + 2048 + h * 128 + p * 32;
        const float* vesrc = ve + (size_t)t * 1024 + h * 128 + p * 32;
#pragma unroll
        for (int q8 = 0; q8 < 4; ++q8) {
            float vf[8];
            unp8(*(const uint4*)(vsrc + q8 * 8), vf);
            float4 e0 = *(const float4*)(vesrc + q8 * 8);
            float4 e1 = *(const float4*)(vesrc + q8 * 8 + 4);
            float ee[8] = {e0.x, e0.y, e0.z, e0.w, e1.x, e1.y, e1.z, e1.w};
#pragma unroll
            for (int j = 0; j < 8; ++j) {
                float vv = l0 * vf[j] + l1 * ee[j];
                sV[(p * 32 + q8 * 8 + j) * 72 + cperm] = f2bf(vv);
            }
        }
    }
    __syncthreads();
    {
        int d = tid >> 1, seg = tid & 1;
        const u16* lsrc = &sV[d * 72 + seg * 32];
        u16* gdst = Vt + ((size_t)h * 128 + d) * 4096 + tb * 64 + seg * 32;
#pragma unroll
        for (int q2 = 0; q2 < 4; ++q2)
            *(uint4*)(gdst + q2 * 8) = *(const uint4*)(lsrc + q2 * 8);
    }
}

// ---------- causal flash attention v9: counted-vmcnt pipeline (T4) ----------
// Structure per tile (raw s_barrier, NEVER vmcnt(0) mid-pipeline except where
// precise): [vmcnt(0): my K landed] barrier -> issue V(t) -> QK -> issue K(t+1)
// -> softmax -> [vmcnt(4): V landed, K(t+1) stays in flight] barrier -> PV.
// K prefetch now spans softmax+PV+next-QK; V spans QK+softmax.
__global__ __launch_bounds__(256) void attn(const u16* __restrict__ Qb,
                                            const u16* __restrict__ Kb,
                                            const u16* __restrict__ Vt,
                                            u16* __restrict__ Y) {
    __shared__ u16 smem[3 * 8192];    // [K0 | K1 | V] 16KB each; epilogue reuses as f32
    const int bid = blockIdx.x;
    const int h = bid & 7;                       // head -> XCD affinity
    const int pid = bid >> 3;
    const int qb = (pid < 32) ? (63 - pid) : (pid - 32);   // complementary pairing
    const int tid = threadIdx.x;
    const int w = tid >> 6, l = tid & 63;
    const int qh = w & 1, kvh = w >> 1;          // wave quadrant
    const int l31 = l & 31, hi = l >> 5;
    const int qg = qb * 64 + qh * 32 + l31;      // this lane's q row (global)
    const int krow = kvh * 32 + l31;

    // Q fragments: qf[dk] covers d = dk*16 + hi*8 .. +7 (B-operand, col=q)
    bf16x8 qf[8];
    {
        const u16* qp = Qb + ((size_t)h * 4096 + qg) * 128;
#pragma unroll
        for (int dk = 0; dk < 8; ++dk) qf[dk] = ld_frag(qp + dk * 16 + hi * 8);
    }

    // running staging pointers (advance by constant stride per tile)
    const u16* kp[4];
    const u16* vp[4];
#pragma unroll
    for (int cc = 0; cc < 4; ++cc) {
        int c = 4 * w + cc;
        int rK = 4 * c + (l >> 4);
        int gsK = (l & 15) ^ (rK & 7);
        kp[cc] = Kb + ((size_t)h * 4096 + rK) * 128 + gsK * 8;
        int rV = 8 * c + (l >> 3);
        int gsV = (l & 7) ^ (rV & 7);
        vp[cc] = Vt + ((size_t)h * 128 + rV) * 4096 + gsV * 8;
    }

    f32x16 o[4] = {};                 // O^T: lane holds d = dt*32+(r&3)+8*(r>>2)+4*hi, q=l31
    float ssum = 0.0f;

    // prologue: stage K(0) into K-buf 0 (waited at loop-top vmcnt(0))
#pragma unroll
    for (int cc = 0; cc < 4; ++cc) {
        gld_lds(kp[cc], smem + (4 * w + cc) * 512);
        kp[cc] += 8192;           // 64 rows * 128
    }

    const int nt = qb + 1;
    int cur = 0;
    for (int t = 0; t < nt; ++t) {
        // ---- top sync: my K(t) loads done (only K outstanding), all waves ----
        asm volatile("s_waitcnt vmcnt(0)" ::: "memory");
        __builtin_amdgcn_s_barrier();
        asm volatile("" ::: "memory");
        __builtin_amdgcn_sched_barrier(0);

        // issue V(t) stage (V buffer free: all waves past PV(t-1))
#pragma unroll
        for (int cc = 0; cc < 4; ++cc) {
            gld_lds(vp[cc], smem + 16384 + (4 * w + cc) * 512);
            vp[cc] += 64;
        }

        // S^T = K · Q on K[cur]
        const u16* sKc = smem + cur * 8192;
        f32x16 st = {};
        __builtin_amdgcn_s_setprio(1);
#pragma unroll
        for (int dk = 0; dk < 8; ++dk) {
            int sl = (2 * dk + hi) ^ (krow & 7);
            bf16x8 kf = ld_frag(sKc + krow * 128 + sl * 8);
            st = __builtin_amdgcn_mfma_f32_32x32x16_bf16(kf, qf[dk], st, 0, 0, 0);
        }
        __builtin_amdgcn_s_setprio(0);

        // issue K(t+1) prefetch (stays in flight across the mid barrier)
        const bool pref = (t + 1 < nt);
        if (pref) {
#pragma unroll
            for (int cc = 0; cc < 4; ++cc) {
                gld_lds(kp[cc], smem + (cur ^ 1) * 8192 + (4 * w + cc) * 512);
                kp[cc] += 8192;
            }
        }

        // no-max softmax (|S| <= ~15.4 by construction); reg r -> kv row
        float pv[16];
        if (t == qb) {
#pragma unroll
            for (int r = 0; r < 16; ++r) {
                int kvg = t * 64 + kvh * 32 + (r & 3) + 8 * (r >> 2) + 4 * hi;
                pv[r] = (kvg <= qg) ? __expf(st[r]) : 0.0f;
            }
        } else {
#pragma unroll
            for (int r = 0; r < 16; ++r) pv[r] = __expf(st[r]);
        }
        float ps = 0.0f;
#pragma unroll
        for (int i = 0; i < 16; ++i) ps += pv[i];
        ssum += ps;

        // PV B-fragments in registers (V bit-2/3-swap perm from prep)
        bf16x8 pb[2];
#pragma unroll
        for (int m = 0; m < 2; ++m) {
            uint4 u;
            u.x = pk_bf16(pv[8 * m + 0], pv[8 * m + 1]);
            u.y = pk_bf16(pv[8 * m + 2], pv[8 * m + 3]);
            u.z = pk_bf16(pv[8 * m + 4], pv[8 * m + 5]);
            u.w = pk_bf16(pv[8 * m + 6], pv[8 * m + 7]);
            pb[m] = __builtin_bit_cast(bf16x8, u);
        }

        // ---- mid sync: my V done (4 oldest); K(t+1) stays in flight ----
        if (pref) { asm volatile("s_waitcnt vmcnt(4)" ::: "memory"); }
        else      { asm volatile("s_waitcnt vmcnt(0)" ::: "memory"); }
        __builtin_amdgcn_s_barrier();
        asm volatile("" ::: "memory");
        __builtin_amdgcn_sched_barrier(0);

        // O^T += V^T · P^T
        const u16* sVc = smem + 16384;
        __builtin_amdgcn_s_setprio(1);
#pragma unroll
        for (int m = 0; m < 2; ++m) {
#pragma unroll
            for (int dt = 0; dt < 4; ++dt) {
                int drow = dt * 32 + l31;
                int sl = (4 * kvh + 2 * m + hi) ^ (drow & 7);
                bf16x8 vf = ld_frag(sVc + drow * 64 + sl * 8);
                o[dt] = __builtin_amdgcn_mfma_f32_32x32x16_bf16(vf, pb[m], o[dt], 0, 0, 0);
            }
        }
        __builtin_amdgcn_s_setprio(0);
        cur ^= 1;
        // no trailing barrier: next top's vmcnt+barrier provides it
    }

    __syncthreads();   // all waves done with PV before smem reuse

    // ---- epilogue: combine kv-halves, normalize, store ----
    ssum += __shfl_xor(ssum, 32);

    float* sO = (float*)smem;               // [2 qh][32 q][132 d-pad] f32 (33792 B)
    float* sS = (float*)smem + 8448;        // [2 qh][32 q] f32
    if (kvh == 1) {
        float* base = sO + (qh * 32 + l31) * 132;
#pragma unroll
        for (int dt = 0; dt < 4; ++dt)
#pragma unroll
            for (int i = 0; i < 4; ++i) {
                int d0 = dt * 32 + i * 8 + hi * 4;
                float4 v = {o[dt][4 * i + 0], o[dt][4 * i + 1],
                            o[dt][4 * i + 2], o[dt][4 * i + 3]};
                *(float4*)(base + d0) = v;
            }
        if (hi == 0) sS[qh * 32 + l31] = ssum;
    }
    __syncthreads();
    if (kvh == 0) {
        float stot = ssum + sS[qh * 32 + l31];
        float inv = 1.0f / stot;
        const float* base = sO + (qh * 32 + l31) * 132;
        u16* yrow = Y + (size_t)qg * 1024 + h * 128;
#pragma unroll
        for (int dt = 0; dt < 4; ++dt)
#pragma unroll
            for (int i = 0; i < 4; ++i) {
                int d0 = dt * 32 + i * 8 + hi * 4;
                float4 prev = *(const float4*)(base + d0);
                u16x4 ov;
                ov.x = f2bf((o[dt][4 * i + 0] + prev.x) * inv);
                ov.y = f2bf((o[dt][4 * i + 1] + prev.y) * inv);
                ov.z = f2bf((o[dt][4 * i + 2] + prev.z) * inv);
                ov.w = f2bf((o[dt][4 * i + 3] + prev.w) * inv);
                *(u16x4*)(yrow + d0) = ov;
            }
    }
}

// ---------- launch ----------
extern "C" void kernel_launch(void* const* d_in, const int* in_sizes, int n_in,
                              void* d_out, int out_size, void* d_ws, size_t ws_size,
                              hipStream_t stream) {
    const float* x = (const float*)d_in[0];
    const float* ve = (const float*)d_in[1];
    const float* qkv_w = (const float*)d_in[2];
    const float* lambdas = (const float*)d_in[3];
    const float* c_proj_w = (const float*)d_in[4];

    char* ws = (char*)d_ws;
    size_t o = 0;
    u16* qkvb = (u16*)(ws + o); o += (size_t)4096 * 3072 * 2;
    u16* xb   = (u16*)(ws + o); o += (size_t)4096 * 1024 * 2;
    u16* wb   = (u16*)(ws + o); o += (size_t)3072 * 1024 * 2;
    u16* cb   = (u16*)(ws + o); o += (size_t)1024 * 1024 * 2;
    u16* Qb   = (u16*)(ws + o); o += (size_t)8 * 4096 * 128 * 2;
    u16* Kb   = (u16*)(ws + o); o += (size_t)8 * 4096 * 128 * 2;
    u16* Vt   = (u16*)(ws + o); o += (size_t)8 * 4096 * 128 * 2;
    u16* Yb   = (u16*)(ws + o); o += (size_t)4096 * 1024 * 2;
    float* ctab = (float*)(ws + o); o += (size_t)4096 * 64 * 4;
    float* stab = (float*)(ws + o); o += (size_t)4096 * 64 * 4;

    cvt3<<<8192, 256, 0, stream>>>(x, qkv_w, c_proj_w, xb, wb, cb);
    rope_tab<<<1024, 256, 0, stream>>>(ctab, stab);
    gemm_nt<true><<<32 * 24, 256, 0, stream>>>(xb, wb, qkvb, 4096, 3072, 1024, 3072);
    prep<<<512, 256, 0, stream>>>(qkvb, ve, lambdas, ctab, stab, Qb, Kb, Vt);
    attn<<<512, 256, 0, stream>>>(Qb, Kb, Vt, Yb);
    gemm_nt<false><<<32 * 8, 256, 0, stream>>>(Yb, cb, d_out, 4096, 1024, 1024, 1024);
}

// Round 11
// 147.323 us; speedup vs baseline: 1.1524x; 1.1524x over previous
//
#include <hip/hip_runtime.h>
#include <hip/hip_bf16.h>

typedef __attribute__((ext_vector_type(4))) float f32x4;
typedef __attribute__((ext_vector_type(16))) float f32x16;
typedef __attribute__((ext_vector_type(8))) __bf16 bf16x8;
typedef unsigned short u16;
typedef unsigned int u32;
typedef __attribute__((ext_vector_type(4))) u16 u16x4;

// ---------- helpers ----------
__device__ __forceinline__ u16 f2bf(float f) {
    u32 u = __builtin_bit_cast(u32, f);
    u32 r = (u + 0x7FFFu + ((u >> 16) & 1u)) >> 16;
    return (u16)r;
}
__device__ __forceinline__ float bf2f(u16 h) {
    return __builtin_bit_cast(float, ((u32)h) << 16);
}
__device__ __forceinline__ bf16x8 ld_frag(const u16* p) {
    uint4 v = *reinterpret_cast<const uint4*>(p);
    return __builtin_bit_cast(bf16x8, v);
}
__device__ __forceinline__ void gld_lds(const u16* gp, u16* lp) {
    __builtin_amdgcn_global_load_lds(
        (const __attribute__((address_space(1))) u32*)gp,
        (__attribute__((address_space(3))) u32*)lp, 16, 0, 0);
}
__device__ __forceinline__ u32 pk_bf16(float lo, float hi) {
    u32 r;
    asm("v_cvt_pk_bf16_f32 %0, %1, %2" : "=v"(r) : "v"(lo), "v"(hi));
    return r;
}
__device__ __forceinline__ void unp8(uint4 v, float* f) {
    f[0] = bf2f((u16)(v.x & 0xffffu)); f[1] = bf2f((u16)(v.x >> 16));
    f[2] = bf2f((u16)(v.y & 0xffffu)); f[3] = bf2f((u16)(v.y >> 16));
    f[4] = bf2f((u16)(v.z & 0xffffu)); f[5] = bf2f((u16)(v.z >> 16));
    f[6] = bf2f((u16)(v.w & 0xffffu)); f[7] = bf2f((u16)(v.w >> 16));
}

// ---------- fused fp32 -> bf16 convert for x / qkv_w / c_proj_w ----------
__global__ __launch_bounds__(256) void cvt3(const float* __restrict__ x,
                                            const float* __restrict__ w,
                                            const float* __restrict__ c,
                                            u16* __restrict__ xb,
                                            u16* __restrict__ wb,
                                            u16* __restrict__ cb) {
    int b = blockIdx.x;
    const float* in;
    u16* out;
    int i;
    if (b < 4096)      { in = x; out = xb; i = b * 256 + threadIdx.x; }
    else if (b < 7168) { in = w; out = wb; i = (b - 4096) * 256 + threadIdx.x; }
    else               { in = c; out = cb; i = (b - 7168) * 256 + threadIdx.x; }
    float4 v = reinterpret_cast<const float4*>(in)[i];
    u16x4 o;
    o.x = f2bf(v.x); o.y = f2bf(v.y); o.z = f2bf(v.z); o.w = f2bf(v.w);
    *reinterpret_cast<u16x4*>(out + 4 * (size_t)i) = o;
}

// ---------- rope tables: ctab/stab [T=4096][64] fp32 ----------
__global__ __launch_bounds__(256) void rope_tab(float* __restrict__ ctab,
                                                float* __restrict__ stab) {
    int i = blockIdx.x * 256 + threadIdx.x;
    int t = i >> 6, j = i & 63;
    float c = 1.0f, s = 0.0f;
    if (j < 32) {
        float f = exp2f(-10.0f * (float)j / 31.0f);
        float th = (float)t * f;
        c = cosf(th); s = sinf(th);
    }
    ctab[i] = c; stab[i] = s;
}

// ---------- NT GEMM: C[M][N] = A[M][K] * B[N][K]^T, bf16 in, fp32 acc ----------
template <bool OUT_BF16>
__global__ __launch_bounds__(256) void gemm_nt(const u16* __restrict__ A,
                                               const u16* __restrict__ B,
                                               void* __restrict__ Cout,
                                               int M, int N, int K, int ldc) {
    __shared__ u16 sA[2][128 * 32];
    __shared__ u16 sB[2][128 * 32];
    const int tid = threadIdx.x;
    const int w = tid >> 6, l = tid & 63;
    const int mb = M >> 7;
    const int bm = blockIdx.x % mb, bn = blockIdx.x / mb;
    const int g = l >> 4, c16 = l & 15;
    const int srow = l >> 2, ssl = l & 3;
    const int wr = w >> 1, wc = w & 1;

    f32x4 acc[4][4] = {};

    auto stage = [&](int bi, int kt) {
#pragma unroll
        for (int cc = 0; cc < 2; ++cc) {
            int c = 2 * w + cc;
            int r = 16 * c + srow;
            int gs = ssl ^ ((r >> 1) & 3);
            gld_lds(A + (size_t)(bm * 128 + r) * K + kt * 32 + gs * 8, &sA[bi][c * 512]);
            gld_lds(B + (size_t)(bn * 128 + r) * K + kt * 32 + gs * 8, &sB[bi][c * 512]);
        }
    };

    const int NT = K >> 5;
    stage(0, 0);
    __syncthreads();
    for (int kt = 0; kt < NT; ++kt) {
        int cur = kt & 1;
        if (kt + 1 < NT) stage(cur ^ 1, kt + 1);
        bf16x8 af[4], bf[4];
#pragma unroll
        for (int mi = 0; mi < 4; ++mi) {
            int r = wr * 64 + mi * 16 + c16;
            int sl = g ^ ((r >> 1) & 3);
            af[mi] = ld_frag(&sA[cur][r * 32 + sl * 8]);
        }
#pragma unroll
        for (int ni = 0; ni < 4; ++ni) {
            int r = wc * 64 + ni * 16 + c16;
            int sl = g ^ ((r >> 1) & 3);
            bf[ni] = ld_frag(&sB[cur][r * 32 + sl * 8]);
        }
#pragma unroll
        for (int mi = 0; mi < 4; ++mi)
#pragma unroll
            for (int ni = 0; ni < 4; ++ni)
                acc[mi][ni] = __builtin_amdgcn_mfma_f32_16x16x32_bf16(
                    af[mi], bf[ni], acc[mi][ni], 0, 0, 0);
        __syncthreads();
    }
#pragma unroll
    for (int mi = 0; mi < 4; ++mi) {
#pragma unroll
        for (int ni = 0; ni < 4; ++ni) {
            int col = bn * 128 + wc * 64 + ni * 16 + c16;
            int row0 = bm * 128 + wr * 64 + mi * 16 + g * 4;
#pragma unroll
            for (int r = 0; r < 4; ++r) {
                if (OUT_BF16)
                    ((u16*)Cout)[(size_t)(row0 + r) * ldc + col] = f2bf(acc[mi][ni][r]);
                else
                    ((float*)Cout)[(size_t)(row0 + r) * ldc + col] = acc[mi][ni][r];
            }
        }
    }
}

// ---------- prep: rmsnorm+rope on q,k (q pre-scaled by ATTN_SCALE); v-mix ----------
// Qb,Kb: [H][T][128] bf16 ; Vt: [H][128][T] bf16 with tokens PERMUTED within
// each 64-block: bits 2<->3 swapped, matching the 32x32x16 MFMA A/B k-slot
// correspondence so attn's in-register P is a valid PV B-operand.
__global__ __launch_bounds__(256) void prep(const u16* __restrict__ qkvb,
                                            const float* __restrict__ ve,
                                            const float* __restrict__ lambdas,
                                            const float* __restrict__ ctab,
                                            const float* __restrict__ stab,
                                            u16* __restrict__ Qb, u16* __restrict__ Kb,
                                            u16* __restrict__ Vt) {
    __shared__ u16 sV[128 * 72];
    const int h = blockIdx.x >> 6, tb = blockIdx.x & 63;
    const int tid = threadIdx.x;
    const int trow = tid >> 2, p = tid & 3;
    const int t = tb * 64 + trow;
    const float l0 = lambdas[0], l1 = lambdas[1];
    // swap bits 2 and 3 of token index within the 64-block
    const int cperm = (trow & 51) | ((trow & 4) << 1) | ((trow & 8) >> 1);

#pragma unroll
    for (int which = 0; which < 2; ++which) {
        const u16* src = qkvb + (size_t)t * 3072 + which * 1024 + h * 128;
        int j0 = p * 16;
        float x1[16], x2[16];
        unp8(*(const uint4*)(src + j0), x1);
        unp8(*(const uint4*)(src + j0 + 8), x1 + 8);
        unp8(*(const uint4*)(src + 64 + j0), x2);
        unp8(*(const uint4*)(src + 64 + j0 + 8), x2 + 8);
        float ss = 0.0f;
#pragma unroll
        for (int e = 0; e < 16; ++e) ss += x1[e] * x1[e] + x2[e] * x2[e];
        ss += __shfl_xor(ss, 1);
        ss += __shfl_xor(ss, 2);
        float rs = rsqrtf(ss * (1.0f / 128.0f) + 1.1920929e-07f);
        float scl = which ? 1.0f : 0.12f;
        rs *= scl;
        u16* dst = (which ? Kb : Qb) + ((size_t)h * 4096 + t) * 128;
#pragma unroll
        for (int e = 0; e < 16; ++e) {
            int j = j0 + e;
            float c = ctab[t * 64 + j], s = stab[t * 64 + j];
            float a = x1[e] * rs, b = x2[e] * rs;
            dst[j] = f2bf(a * c + b * s);
            dst[j + 64] = f2bf(b * c - a * s);
        }
    }
    {
        const u16* vsrc = qkvb + (size_t)t * 3072 + 2048 + h * 128 + p * 32;
        const float* vesrc = ve + (size_t)t * 1024 + h * 128 + p * 32;
#pragma unroll
        for (int q8 = 0; q8 < 4; ++q8) {
            float vf[8];
            unp8(*(const uint4*)(vsrc + q8 * 8), vf);
            float4 e0 = *(const float4*)(vesrc + q8 * 8);
            float4 e1 = *(const float4*)(vesrc + q8 * 8 + 4);
            float ee[8] = {e0.x, e0.y, e0.z, e0.w, e1.x, e1.y, e1.z, e1.w};
#pragma unroll
            for (int j = 0; j < 8; ++j) {
                float vv = l0 * vf[j] + l1 * ee[j];
                sV[(p * 32 + q8 * 8 + j) * 72 + cperm] = f2bf(vv);
            }
        }
    }
    __syncthreads();
    {
        int d = tid >> 1, seg = tid & 1;
        const u16* lsrc = &sV[d * 72 + seg * 32];
        u16* gdst = Vt + ((size_t)h * 128 + d) * 4096 + tb * 64 + seg * 32;
#pragma unroll
        for (int q2 = 0; q2 < 4; ++q2)
            *(uint4*)(gdst + q2 * 8) = *(const uint4*)(lsrc + q2 * 8);
    }
}

// ---------- causal flash attention v10: uniform-length double-segment ----------
// grid 512 = (h, j in 32, half in 2). Each block runs TWO segments serially:
//   seg0: kv-half `half`   of q-block qb=j
//   seg1: kv-half `1-half` of q-block qb=63-j
// Length = floor((j+1)/2) + ceil((64-j)/2) = 32..33 tiles for EVERY block ->
// no straggler CU (R10's wall was the 64-tile qb=63 block). Partial O (fp32)
// + partial ssum; exact combine (no-max softmax). Core = R9's 85us body.
#define OPHALF 4194304  /* 8*4096*128 floats = 16 MB per part */
__global__ __launch_bounds__(256) void attn(const u16* __restrict__ Qb,
                                            const u16* __restrict__ Kb,
                                            const u16* __restrict__ Vt,
                                            float* __restrict__ Op,
                                            float* __restrict__ ssumP) {
    __shared__ u16 smem[3 * 8192];    // [K0 | K1 | V] 16KB each; epilogue reuses as f32
    const int bid = blockIdx.x;
    const int h = bid & 7;                       // head -> XCD affinity
    const int pid = bid >> 3;                    // 0..63
    const int j = pid >> 1;                      // 0..31
    const int half = pid & 1;
    const int tid = threadIdx.x;
    const int w = tid >> 6, l = tid & 63;
    const int qh = w & 1, kvh = w >> 1;          // wave quadrant
    const int l31 = l & 31, hi = l >> 5;
    const int krow = kvh * 32 + l31;

    for (int seg = 0; seg < 2; ++seg) {
        const int qb = seg ? (63 - j) : j;
        const int part = seg ? (1 - half) : half;
        const int s = (qb + 1) >> 1;
        const int t0 = part ? s : 0;
        const int t1 = part ? (qb + 1) : s;
        const int qg = qb * 64 + qh * 32 + l31;  // this lane's q row (global)

        // Q fragments: qf[dk] covers d = dk*16 + hi*8 .. +7 (B-operand, col=q)
        bf16x8 qf[8];
        {
            const u16* qp = Qb + ((size_t)h * 4096 + qg) * 128;
#pragma unroll
            for (int dk = 0; dk < 8; ++dk) qf[dk] = ld_frag(qp + dk * 16 + hi * 8);
        }

        // running staging pointers (advance by constant stride per tile)
        const u16* kp[4];
        const u16* vp[4];
#pragma unroll
        for (int cc = 0; cc < 4; ++cc) {
            int c = 4 * w + cc;
            int rK = 4 * c + (l >> 4);
            int gsK = (l & 15) ^ (rK & 7);
            kp[cc] = Kb + ((size_t)h * 4096 + t0 * 64 + rK) * 128 + gsK * 8;
            int rV = 8 * c + (l >> 3);
            int gsV = (l & 7) ^ (rV & 7);
            vp[cc] = Vt + ((size_t)h * 128 + rV) * 4096 + t0 * 64 + gsV * 8;
        }

        f32x16 o[4] = {};   // O^T: lane holds d = dt*32+(r&3)+8*(r>>2)+4*hi, q=l31
        float ssum = 0.0f;

        if (t0 < t1) {
            // prologue: stage K(t0) into K-buf 0
#pragma unroll
            for (int cc = 0; cc < 4; ++cc) {
                gld_lds(kp[cc], smem + (4 * w + cc) * 512);
                kp[cc] += 8192;           // 64 rows * 128
            }
            __syncthreads();

            int cur = 0;
            for (int t = t0; t < t1; ++t) {
                // issue K(t+1) prefetch + V(t) stage
                if (t + 1 < t1) {
#pragma unroll
                    for (int cc = 0; cc < 4; ++cc) {
                        gld_lds(kp[cc], smem + (cur ^ 1) * 8192 + (4 * w + cc) * 512);
                        kp[cc] += 8192;
                    }
                }
#pragma unroll
                for (int cc = 0; cc < 4; ++cc) {
                    gld_lds(vp[cc], smem + 16384 + (4 * w + cc) * 512);
                    vp[cc] += 64;
                }

                // S^T = K · Q on K[cur]
                const u16* sKc = smem + cur * 8192;
                f32x16 st = {};
                __builtin_amdgcn_s_setprio(1);
#pragma unroll
                for (int dk = 0; dk < 8; ++dk) {
                    int sl = (2 * dk + hi) ^ (krow & 7);
                    bf16x8 kf = ld_frag(sKc + krow * 128 + sl * 8);
                    st = __builtin_amdgcn_mfma_f32_32x32x16_bf16(kf, qf[dk], st, 0, 0, 0);
                }
                __builtin_amdgcn_s_setprio(0);

                // no-max softmax (|S| <= ~15.4 by construction); reg r -> kv row
                float pv[16];
                if (t == qb) {
#pragma unroll
                    for (int r = 0; r < 16; ++r) {
                        int kvg = t * 64 + kvh * 32 + (r & 3) + 8 * (r >> 2) + 4 * hi;
                        pv[r] = (kvg <= qg) ? __expf(st[r]) : 0.0f;
                    }
                } else {
#pragma unroll
                    for (int r = 0; r < 16; ++r) pv[r] = __expf(st[r]);
                }
                float ps = 0.0f;
#pragma unroll
                for (int i = 0; i < 16; ++i) ps += pv[i];
                ssum += ps;

                // PV B-fragments in registers (V bit-2/3-swap perm from prep)
                bf16x8 pb[2];
#pragma unroll
                for (int m = 0; m < 2; ++m) {
                    uint4 u;
                    u.x = pk_bf16(pv[8 * m + 0], pv[8 * m + 1]);
                    u.y = pk_bf16(pv[8 * m + 2], pv[8 * m + 3]);
                    u.z = pk_bf16(pv[8 * m + 4], pv[8 * m + 5]);
                    u.w = pk_bf16(pv[8 * m + 6], pv[8 * m + 7]);
                    pb[m] = __builtin_bit_cast(bf16x8, u);
                }

                __syncthreads();   // V(t) landed (also drains K(t+1) prefetch)

                // O^T += V^T · P^T
                const u16* sVc = smem + 16384;
                __builtin_amdgcn_s_setprio(1);
#pragma unroll
                for (int m = 0; m < 2; ++m) {
#pragma unroll
                    for (int dt = 0; dt < 4; ++dt) {
                        int drow = dt * 32 + l31;
                        int sl = (4 * kvh + 2 * m + hi) ^ (drow & 7);
                        bf16x8 vf = ld_frag(sVc + drow * 64 + sl * 8);
                        o[dt] = __builtin_amdgcn_mfma_f32_32x32x16_bf16(vf, pb[m], o[dt], 0, 0, 0);
                    }
                }
                __builtin_amdgcn_s_setprio(0);
                __syncthreads();   // all waves done with V-buf; K[cur^1] ready
                cur ^= 1;
            }
        } else {
            __syncthreads();   // keep block converged for epilogue smem use
        }

        // ---- segment epilogue: combine kv-halves, store partial O + ssum ----
        ssum += __shfl_xor(ssum, 32);

        float* sO = (float*)smem;               // [2 qh][32 q][132 d-pad] f32
        float* sS = (float*)smem + 8448;        // [2 qh][32 q] f32
        if (kvh == 1) {
            float* base = sO + (qh * 32 + l31) * 132;
#pragma unroll
            for (int dt = 0; dt < 4; ++dt)
#pragma unroll
                for (int i = 0; i < 4; ++i) {
                    int d0 = dt * 32 + i * 8 + hi * 4;
                    float4 v = {o[dt][4 * i + 0], o[dt][4 * i + 1],
                                o[dt][4 * i + 2], o[dt][4 * i + 3]};
                    *(float4*)(base + d0) = v;
                }
            if (hi == 0) sS[qh * 32 + l31] = ssum;
        }
        __syncthreads();
        if (kvh == 0) {
            float stot = ssum + sS[qh * 32 + l31];
            const float* base = sO + (qh * 32 + l31) * 132;
            float* orow = Op + (size_t)part * OPHALF + ((size_t)(h * 4096 + qg)) * 128;
#pragma unroll
            for (int dt = 0; dt < 4; ++dt)
#pragma unroll
                for (int i = 0; i < 4; ++i) {
                    int d0 = dt * 32 + i * 8 + hi * 4;
                    float4 prev = *(const float4*)(base + d0);
                    float4 ov = {o[dt][4 * i + 0] + prev.x, o[dt][4 * i + 1] + prev.y,
                                 o[dt][4 * i + 2] + prev.z, o[dt][4 * i + 3] + prev.w};
                    *(float4*)(orow + d0) = ov;
                }
            if (hi == 0) ssumP[part * 32768 + h * 4096 + qg] = stot;
        }
        __syncthreads();   // epilogue smem reads done before next segment stages
    }
}

// ---------- combine parts: y = (O0+O1)/(s0+s1) -> Y bf16 [T][1024] ----------
__global__ __launch_bounds__(256) void combine(const float* __restrict__ Op,
                                               const float* __restrict__ ssumP,
                                               u16* __restrict__ Y) {
    int i = blockIdx.x * 256 + threadIdx.x;   // over [8][4096][32] float4s
    int d4 = i & 31;
    int hq = i >> 5;
    int h = hq >> 12, q = hq & 4095;
    float4 a = ((const float4*)Op)[i];
    float4 b = ((const float4*)(Op + OPHALF))[i];
    float inv = 1.0f / (ssumP[hq] + ssumP[32768 + hq]);
    u16x4 ov;
    ov.x = f2bf((a.x + b.x) * inv);
    ov.y = f2bf((a.y + b.y) * inv);
    ov.z = f2bf((a.z + b.z) * inv);
    ov.w = f2bf((a.w + b.w) * inv);
    *(u16x4*)(Y + (size_t)q * 1024 + h * 128 + d4 * 4) = ov;
}

// ---------- launch ----------
extern "C" void kernel_launch(void* const* d_in, const int* in_sizes, int n_in,
                              void* d_out, int out_size, void* d_ws, size_t ws_size,
                              hipStream_t stream) {
    const float* x = (const float*)d_in[0];
    const float* ve = (const float*)d_in[1];
    const float* qkv_w = (const float*)d_in[2];
    const float* lambdas = (const float*)d_in[3];
    const float* c_proj_w = (const float*)d_in[4];

    char* ws = (char*)d_ws;
    size_t o = 0;
    u16* qkvb = (u16*)(ws + o); o += (size_t)4096 * 3072 * 2;   // dead after prep
    u16* xb   = (u16*)(ws + o); o += (size_t)4096 * 1024 * 2;   // dead after gemm1
    u16* wb   = (u16*)(ws + o); o += (size_t)3072 * 1024 * 2;   // dead after gemm1
    u16* cb   = (u16*)(ws + o); o += (size_t)1024 * 1024 * 2;
    u16* Qb   = (u16*)(ws + o); o += (size_t)8 * 4096 * 128 * 2;
    u16* Kb   = (u16*)(ws + o); o += (size_t)8 * 4096 * 128 * 2;
    u16* Vt   = (u16*)(ws + o); o += (size_t)8 * 4096 * 128 * 2;
    u16* Yb   = (u16*)(ws + o); o += (size_t)4096 * 1024 * 2;
    float* ctab = (float*)(ws + o); o += (size_t)4096 * 64 * 4;
    float* stab = (float*)(ws + o); o += (size_t)4096 * 64 * 4;
    // partial O (32 MB) reuses qkvb+xb (dead by attn); partial ssum reuses wb.
    float* Op    = (float*)qkvb;
    float* ssumP = (float*)wb;

    cvt3<<<8192, 256, 0, stream>>>(x, qkv_w, c_proj_w, xb, wb, cb);
    rope_tab<<<1024, 256, 0, stream>>>(ctab, stab);
    gemm_nt<true><<<32 * 24, 256, 0, stream>>>(xb, wb, qkvb, 4096, 3072, 1024, 3072);
    prep<<<512, 256, 0, stream>>>(qkvb, ve, lambdas, ctab, stab, Qb, Kb, Vt);
    attn<<<512, 256, 0, stream>>>(Qb, Kb, Vt, Op, ssumP);
    combine<<<4096, 256, 0, stream>>>(Op, ssumP, Yb);
    gemm_nt<false><<<32 * 8, 256, 0, stream>>>(Yb, cb, d_out, 4096, 1024, 1024, 1024);
}